// Round 8
// baseline (117.205 us; speedup 1.0000x reference)
//
#include <hip/hip_runtime.h>
#include <math.h>

#define IN_F 256
#define OUT_F 128
#define NHEAD 2
#define ALPHA 0.2f
#define NN 4096          // compile-time N (problem-fixed)
#define NCAP 256         // max neighbors/row (max degree ~45 + diag)

typedef __attribute__((ext_vector_type(8))) short short8;
typedef __attribute__((ext_vector_type(4))) float f32x4;
typedef const __attribute__((address_space(1))) void* gas_ptr;
typedef __attribute__((address_space(3))) void* las_ptr;

__device__ __forceinline__ void async_copy16(const void* g, void* l) {
  __builtin_amdgcn_global_load_lds((gas_ptr)g, (las_ptr)l, 16, 0, 0);
}

__device__ __forceinline__ ushort f2bf(float f) {
  unsigned u = __float_as_uint(f);
  u += 0x7fffu + ((u >> 16) & 1u);  // RNE
  return (ushort)(u >> 16);
}

__device__ __forceinline__ float lrelu(float t) { return t > 0.f ? t : ALPHA * t; }

// ---------------------------------------------------------------------------
// prep_w: Wt[h][o][k] = bf16(W[h][k][o])  (transpose + cast; 64 blocks)
// ---------------------------------------------------------------------------
__global__ __launch_bounds__(256) void prep_w(
    const float* __restrict__ W, ushort* __restrict__ Wt) {
  int p = blockIdx.x * 256 + threadIdx.x;   // 16384 ushort4 outputs
  int h = p >> 13;
  int rem = p & 8191;
  int c = rem >> 7;       // k-quad 0..63
  int o = rem & 127;
  const float* wsrc = W + h * (IN_F * OUT_F) + (4 * c) * OUT_F + o;
  ushort4 ov;
  ov.x = f2bf(wsrc[0 * OUT_F]);
  ov.y = f2bf(wsrc[1 * OUT_F]);
  ov.z = f2bf(wsrc[2 * OUT_F]);
  ov.w = f2bf(wsrc[3 * OUT_F]);
  *(ushort4*)(Wt + ((size_t)h * OUT_F + o) * IN_F + 4 * c) = ov;
}

// ---------------------------------------------------------------------------
// gemm_mfma: M-tile 16 (512 blocks -> 2 blocks/CU, 2 waves/SIMD for latency
// hiding). Each wave: 16 rows x 32 cols (wc = wave). A: 4 independent
// dwordx4 prefetch -> bf16 -> LDS. B: async global_load_lds width=16.
// Fused e1/e2 epilogue.
// ---------------------------------------------------------------------------
__global__ __launch_bounds__(256) void gemm_mfma(
    const float* __restrict__ x, const ushort* __restrict__ Wt,
    const float* __restrict__ a,
    float* __restrict__ xt, float* __restrict__ e1, float* __restrict__ e2) {
  __shared__ ushort sA[16 * 64];    //  2 KB
  __shared__ ushort sB[128 * 64];   // 16 KB
  __shared__ float sa[2 * OUT_F];
  __shared__ float s_pe1[4][16], s_pe2[4][16];

  const int h = blockIdx.y;
  const int rowBase = blockIdx.x * 16;
  const int tid = threadIdx.x;
  const int wave = tid >> 6, lane = tid & 63;
  const int wc = wave;              // col slice: wc*32 .. wc*32+31
  const int q = lane >> 4, l16 = lane & 15;
  const int ar = tid >> 4;          // A row 0..15
  const int ac = (tid & 15) * 4;    // A col-quad 0..60

  // A prefetch: 4 independent float4 loads (one per K-chunk)
  const float* xrow = x + (size_t)(rowBase + ar) * IN_F + ac;
  float4 ax[4];
#pragma unroll
  for (int c = 0; c < 4; ++c) ax[c] = *(const float4*)(xrow + 64 * c);

  sa[tid] = a[h * (2 * OUT_F) + tid];

  f32x4 acc[2];
  acc[0] = (f32x4)(0.0f);
  acc[1] = (f32x4)(0.0f);

  const char* wbase = (const char*)(Wt + (size_t)h * (OUT_F * IN_F));

#pragma unroll
  for (int c = 0; c < 4; ++c) {
    const int k0 = c * 64;
    // B tile: 128x64 bf16 = 1024 granules of 16B, 4/thread (async)
#pragma unroll
    for (int it = 0; it < 4; ++it) {
      int g = it * 256 + tid;
      int r = g >> 3, c8 = g & 7;
      async_copy16(wbase + r * 512 + k0 * 2 + c8 * 16,
                   (char*)sB + (size_t)(it * 256 + wave * 64) * 16);
    }
    // A tile: cast prefetched regs -> LDS (ushort4 = 8B per thread)
    {
      float4 va = ax[c];
      ushort4 pk;
      pk.x = f2bf(va.x); pk.y = f2bf(va.y);
      pk.z = f2bf(va.z); pk.w = f2bf(va.w);
      *(ushort4*)(sA + ar * 64 + ac) = pk;
    }
    __syncthreads();

#pragma unroll
    for (int ks = 0; ks < 64; ks += 32) {
      short8 af = *(const short8*)(sA + l16 * 64 + ks + q * 8);
#pragma unroll
      for (int ct = 0; ct < 2; ++ct) {
        int col = wc * 32 + ct * 16 + l16;
        short8 bf = *(const short8*)(sB + col * 64 + ks + q * 8);
        acc[ct] = __builtin_amdgcn_mfma_f32_16x16x32_bf16(af, bf, acc[ct], 0, 0, 0);
      }
    }
    __syncthreads();
  }

  // epilogue 1: store xt (D: row = q*4+reg, col = l16)
#pragma unroll
  for (int ct = 0; ct < 2; ++ct) {
    int col = wc * 32 + ct * 16 + l16;
#pragma unroll
    for (int reg = 0; reg < 4; ++reg) {
      int row = rowBase + q * 4 + reg;
      xt[((size_t)h * NN + row) * OUT_F + col] = acc[ct][reg];
    }
  }

  // epilogue 2: fused e1/e2 (per-wave partial over its 32 cols)
  float pe1[4], pe2[4];
#pragma unroll
  for (int reg = 0; reg < 4; ++reg) { pe1[reg] = 0.f; pe2[reg] = 0.f; }
#pragma unroll
  for (int ct = 0; ct < 2; ++ct) {
    int col = wc * 32 + ct * 16 + l16;
    float a1v = sa[col], a2v = sa[OUT_F + col];
#pragma unroll
    for (int reg = 0; reg < 4; ++reg) {
      pe1[reg] = fmaf(acc[ct][reg], a1v, pe1[reg]);
      pe2[reg] = fmaf(acc[ct][reg], a2v, pe2[reg]);
    }
  }
#pragma unroll
  for (int off = 1; off < 16; off <<= 1) {
#pragma unroll
    for (int reg = 0; reg < 4; ++reg) {
      pe1[reg] += __shfl_xor(pe1[reg], off, 64);
      pe2[reg] += __shfl_xor(pe2[reg], off, 64);
    }
  }
  if (l16 == 0) {
#pragma unroll
    for (int reg = 0; reg < 4; ++reg) {
      s_pe1[wave][q * 4 + reg] = pe1[reg];
      s_pe2[wave][q * 4 + reg] = pe2[reg];
    }
  }
  __syncthreads();
  if (tid < 16) {
    float v1 = (s_pe1[0][tid] + s_pe1[1][tid]) + (s_pe1[2][tid] + s_pe1[3][tid]);
    float v2 = (s_pe2[0][tid] + s_pe2[1][tid]) + (s_pe2[2][tid] + s_pe2[3][tid]);
    e1[(size_t)h * NN + rowBase + tid] = v1;
    e2[(size_t)h * NN + rowBase + tid] = v2;
  }
}

// ---------------------------------------------------------------------------
// gat_aggregate (R6-proven): 1 row/block, hoisted scan, parallel reductions,
// x4-unrolled gather. Output raw-reshape layout [h][i][o].
// ---------------------------------------------------------------------------
__global__ __launch_bounds__(256) void gat_aggregate(
    const float* __restrict__ adj, const float* __restrict__ xt,
    const float* __restrict__ e1, const float* __restrict__ e2,
    float* __restrict__ out) {
  __shared__ int s_nbr[NCAP];
  __shared__ float s_sc0[NCAP];
  __shared__ float s_sc1[NCAP];
  __shared__ int s_cnt;
  __shared__ float s_red[4][2];

  const int i = blockIdx.x;
  const int tid = threadIdx.x;
  const int wave = tid >> 6, lane = tid & 63;
  if (tid == 0) s_cnt = 0;
  __syncthreads();

  // phase 1: scan (all 4 wave-wide loads in flight before processing)
  const float4* arow4 = (const float4*)(adj + (size_t)i * NN);
  float4 v[4];
#pragma unroll
  for (int it = 0; it < 4; ++it) v[it] = arow4[tid + it * 256];

#pragma unroll
  for (int it = 0; it < 4; ++it) {
    int j = (tid + it * 256) * 4;
    float vals[4] = {v[it].x, v[it].y, v[it].z, v[it].w};
#pragma unroll
    for (int s = 0; s < 4; ++s) {
      if (vals[s] > 0.f || j + s == i) {
        int p = atomicAdd(&s_cnt, 1);
        if (p < NCAP) s_nbr[p] = j + s;
      }
    }
  }
  __syncthreads();
  const int m = s_cnt < NCAP ? s_cnt : NCAP;

  // phase 2: scores (non-divergent, one gather per thread)
  const float e10 = e1[i];
  const float e11 = e1[NN + i];
  if (tid < m) {
    int j = s_nbr[tid];
    s_sc0[tid] = lrelu(e10 + e2[j]);
    s_sc1[tid] = lrelu(e11 + e2[NN + j]);
  }
  __syncthreads();

  // phase 3: parallel max (both heads)
  float t0 = (tid < m) ? s_sc0[tid] : -3.0e38f;
  float t1 = (tid < m) ? s_sc1[tid] : -3.0e38f;
#pragma unroll
  for (int off = 32; off > 0; off >>= 1) {
    t0 = fmaxf(t0, __shfl_xor(t0, off, 64));
    t1 = fmaxf(t1, __shfl_xor(t1, off, 64));
  }
  if (lane == 0) { s_red[wave][0] = t0; s_red[wave][1] = t1; }
  __syncthreads();
  const float mx0 = fmaxf(fmaxf(s_red[0][0], s_red[1][0]), fmaxf(s_red[2][0], s_red[3][0]));
  const float mx1 = fmaxf(fmaxf(s_red[0][1], s_red[1][1]), fmaxf(s_red[2][1], s_red[3][1]));
  __syncthreads();

  // phase 4: exp + parallel sum
  float g0 = 0.f, g1 = 0.f;
  if (tid < m) {
    g0 = __expf(s_sc0[tid] - mx0); s_sc0[tid] = g0;
    g1 = __expf(s_sc1[tid] - mx1); s_sc1[tid] = g1;
  }
#pragma unroll
  for (int off = 32; off > 0; off >>= 1) {
    g0 += __shfl_xor(g0, off, 64);
    g1 += __shfl_xor(g1, off, 64);
  }
  if (lane == 0) { s_red[wave][0] = g0; s_red[wave][1] = g1; }
  __syncthreads();
  const float l0 = (s_red[0][0] + s_red[1][0]) + (s_red[2][0] + s_red[3][0]);
  const float l1 = (s_red[0][1] + s_red[1][1]) + (s_red[2][1] + s_red[3][1]);

  // phase 5: gather-accumulate (x4 unrolled), post-normalize, ELU
  const int h = tid >> 7;
  const int o = tid & 127;
  const float* pp = h ? s_sc1 : s_sc0;
  const float linv = 1.0f / (h ? l1 : l0);
  const float* xth = xt + (size_t)h * NN * OUT_F + o;

  float acc = 0.f;
  int k = 0;
  for (; k + 4 <= m; k += 4) {
    int j0 = s_nbr[k], j1 = s_nbr[k + 1], j2 = s_nbr[k + 2], j3 = s_nbr[k + 3];
    float q0 = pp[k], q1 = pp[k + 1], q2 = pp[k + 2], q3 = pp[k + 3];
    float w0 = xth[(size_t)j0 * OUT_F], w1 = xth[(size_t)j1 * OUT_F];
    float w2 = xth[(size_t)j2 * OUT_F], w3 = xth[(size_t)j3 * OUT_F];
    acc = fmaf(q0, w0, acc); acc = fmaf(q1, w1, acc);
    acc = fmaf(q2, w2, acc); acc = fmaf(q3, w3, acc);
  }
  for (; k < m; ++k) acc = fmaf(pp[k], xth[(size_t)s_nbr[k] * OUT_F], acc);

  acc *= linv;
  float r = acc > 0.f ? acc : (__expf(acc) - 1.0f);
  out[((size_t)h * NN + i) * OUT_F + o] = r;
}

// ---------------------------------------------------------------------------
extern "C" void kernel_launch(void* const* d_in, const int* in_sizes, int n_in,
                              void* d_out, int out_size, void* d_ws, size_t ws_size,
                              hipStream_t stream) {
  const float* x   = (const float*)d_in[0];
  const float* adj = (const float*)d_in[1];
  const float* W   = (const float*)d_in[2];
  const float* a   = (const float*)d_in[3];
  float* out = (float*)d_out;

  float* xt = (float*)d_ws;                                  // H*N*OUT_F f32 (4 MB)
  float* e1 = xt + (size_t)NHEAD * NN * OUT_F;               // H*N
  float* e2 = e1 + (size_t)NHEAD * NN;                       // H*N
  ushort* Wt = (ushort*)(e2 + (size_t)NHEAD * NN);           // H*OUT_F*IN_F bf16

  prep_w<<<64, 256, 0, stream>>>(W, Wt);
  gemm_mfma<<<dim3(NN / 16, NHEAD), 256, 0, stream>>>(x, Wt, a, xt, e1, e2);
  gat_aggregate<<<NN, 256, 0, stream>>>(adj, xt, e1, e2, out);
}

// Round 9
// 112.451 us; speedup vs baseline: 1.0423x; 1.0423x over previous
//
#include <hip/hip_runtime.h>
#include <math.h>

#define IN_F 256
#define OUT_F 128
#define NHEAD 2
#define ALPHA 0.2f
#define NN 4096          // compile-time N (problem-fixed)
#define NCAP 128         // max neighbors/row (max degree ~45+1; 128 = 23 sigma)

typedef __attribute__((ext_vector_type(8))) short short8;
typedef __attribute__((ext_vector_type(4))) float f32x4;
typedef const __attribute__((address_space(1))) void* gas_ptr;
typedef __attribute__((address_space(3))) void* las_ptr;

__device__ __forceinline__ void async_copy16(const void* g, void* l) {
  __builtin_amdgcn_global_load_lds((gas_ptr)g, (las_ptr)l, 16, 0, 0);
}

__device__ __forceinline__ ushort f2bf(float f) {
  unsigned u = __float_as_uint(f);
  u += 0x7fffu + ((u >> 16) & 1u);  // RNE
  return (ushort)(u >> 16);
}

__device__ __forceinline__ float lrelu(float t) { return t > 0.f ? t : ALPHA * t; }

// ---------------------------------------------------------------------------
// prep_w: Wt[h][o][k] = bf16(W[h][k][o])  (transpose + cast; 64 blocks)
// ---------------------------------------------------------------------------
__global__ __launch_bounds__(256) void prep_w(
    const float* __restrict__ W, ushort* __restrict__ Wt) {
  int p = blockIdx.x * 256 + threadIdx.x;   // 16384 ushort4 outputs
  int h = p >> 13;
  int rem = p & 8191;
  int c = rem >> 7;       // k-quad 0..63
  int o = rem & 127;
  const float* wsrc = W + h * (IN_F * OUT_F) + (4 * c) * OUT_F + o;
  ushort4 ov;
  ov.x = f2bf(wsrc[0 * OUT_F]);
  ov.y = f2bf(wsrc[1 * OUT_F]);
  ov.z = f2bf(wsrc[2 * OUT_F]);
  ov.w = f2bf(wsrc[3 * OUT_F]);
  *(ushort4*)(Wt + ((size_t)h * OUT_F + o) * IN_F + 4 * c) = ov;
}

// ---------------------------------------------------------------------------
// gemm_mfma (R7-proven best): M32 tile, 256 blocks. A: 8 independent dwordx4
// prefetched at entry -> bf16 -> LDS. B: async global_load_lds width=16.
// Fused e1/e2 epilogue.
// ---------------------------------------------------------------------------
__global__ __launch_bounds__(256) void gemm_mfma(
    const float* __restrict__ x, const ushort* __restrict__ Wt,
    const float* __restrict__ a,
    float* __restrict__ xt, float* __restrict__ e1, float* __restrict__ e2) {
  __shared__ ushort sA[32 * 64];    //  4 KB
  __shared__ ushort sB[128 * 64];   // 16 KB
  __shared__ float sa[2 * OUT_F];
  __shared__ float se1[32], se2[32];

  const int h = blockIdx.y;
  const int rowBase = blockIdx.x * 32;
  const int tid = threadIdx.x;
  const int wave = tid >> 6, lane = tid & 63;
  const int wr = wave & 1, wc = wave >> 1;
  const int q = lane >> 4, l16 = lane & 15;
  const int ar = tid >> 3;          // A row 0..31
  const int ak = (tid & 7) * 8;     // A col-octet 0..56

  // A prefetch: full row-slice for all 4 chunks (8 float4s, independent)
  const float* xrow = x + (size_t)(rowBase + ar) * IN_F + ak;
  float4 ax[8];
#pragma unroll
  for (int c = 0; c < 4; ++c) {
    ax[2 * c]     = *(const float4*)(xrow + 64 * c);
    ax[2 * c + 1] = *(const float4*)(xrow + 64 * c + 4);
  }

  sa[tid] = a[h * (2 * OUT_F) + tid];

  f32x4 acc[4];
#pragma unroll
  for (int i = 0; i < 4; ++i) acc[i] = (f32x4)(0.0f);

  const char* wbase = (const char*)(Wt + (size_t)h * (OUT_F * IN_F));

#pragma unroll
  for (int c = 0; c < 4; ++c) {
    const int k0 = c * 64;
    // B tile: 128x64 bf16 = 1024 granules of 16B, 4/thread (async)
#pragma unroll
    for (int it = 0; it < 4; ++it) {
      int g = it * 256 + tid;
      int r = g >> 3, c8 = g & 7;
      async_copy16(wbase + r * 512 + k0 * 2 + c8 * 16,
                   (char*)sB + (size_t)(it * 256 + wave * 64) * 16);
    }
    // A tile: cast prefetched regs -> LDS
    {
      float4 va = ax[2 * c], vb = ax[2 * c + 1];
      union { short8 s8; ushort u[8]; } pk;
      pk.u[0] = f2bf(va.x); pk.u[1] = f2bf(va.y);
      pk.u[2] = f2bf(va.z); pk.u[3] = f2bf(va.w);
      pk.u[4] = f2bf(vb.x); pk.u[5] = f2bf(vb.y);
      pk.u[6] = f2bf(vb.z); pk.u[7] = f2bf(vb.w);
      *(short8*)(sA + ar * 64 + ak) = pk.s8;
    }
    __syncthreads();

#pragma unroll
    for (int ks = 0; ks < 64; ks += 32) {
      short8 af = *(const short8*)(sA + (wr * 16 + l16) * 64 + ks + q * 8);
#pragma unroll
      for (int ct = 0; ct < 4; ++ct) {
        int col = wc * 64 + ct * 16 + l16;
        short8 bf = *(const short8*)(sB + col * 64 + ks + q * 8);
        acc[ct] = __builtin_amdgcn_mfma_f32_16x16x32_bf16(af, bf, acc[ct], 0, 0, 0);
      }
    }
    __syncthreads();
  }

  // epilogue 1: store xt (D: row = q*4+reg, col = l16)
#pragma unroll
  for (int ct = 0; ct < 4; ++ct) {
    int col = wc * 64 + ct * 16 + l16;
#pragma unroll
    for (int reg = 0; reg < 4; ++reg) {
      int row = rowBase + wr * 16 + q * 4 + reg;
      xt[((size_t)h * NN + row) * OUT_F + col] = acc[ct][reg];
    }
  }

  // epilogue 2: fused e1/e2
  float pe1[4], pe2[4];
#pragma unroll
  for (int reg = 0; reg < 4; ++reg) { pe1[reg] = 0.f; pe2[reg] = 0.f; }
#pragma unroll
  for (int ct = 0; ct < 4; ++ct) {
    int col = wc * 64 + ct * 16 + l16;
    float a1v = sa[col], a2v = sa[OUT_F + col];
#pragma unroll
    for (int reg = 0; reg < 4; ++reg) {
      pe1[reg] = fmaf(acc[ct][reg], a1v, pe1[reg]);
      pe2[reg] = fmaf(acc[ct][reg], a2v, pe2[reg]);
    }
  }
#pragma unroll
  for (int off = 1; off < 16; off <<= 1) {
#pragma unroll
    for (int reg = 0; reg < 4; ++reg) {
      pe1[reg] += __shfl_xor(pe1[reg], off, 64);
      pe2[reg] += __shfl_xor(pe2[reg], off, 64);
    }
  }
  if (wc == 0 && l16 == 0) {
#pragma unroll
    for (int reg = 0; reg < 4; ++reg) {
      int r = wr * 16 + q * 4 + reg;
      se1[r] = pe1[reg];
      se2[r] = pe2[reg];
    }
  }
  __syncthreads();
  if (wc == 1 && l16 == 0) {
#pragma unroll
    for (int reg = 0; reg < 4; ++reg) {
      int r = wr * 16 + q * 4 + reg;
      se1[r] += pe1[reg];
      se2[r] += pe2[reg];
    }
  }
  __syncthreads();
  if (tid < 32) {
    e1[(size_t)h * NN + rowBase + tid] = se1[tid];
    e2[(size_t)h * NN + rowBase + tid] = se2[tid];
  }
}

// ---------------------------------------------------------------------------
// gat_aggregate: WAVE-per-row, barrier-free. 4 rows/block, grid 1024.
// Compaction via __ballot + popcount prefix (no atomics, no barriers).
// Scan: 16 float4/lane all in flight. Softmax in registers (wave shfl).
// Gather: lane -> (head = lane>>5, 4 cols), float4 loads, x4 unrolled.
// Output raw-reshape layout [h][i][o].
// ---------------------------------------------------------------------------
__global__ __launch_bounds__(256) void gat_aggregate(
    const float* __restrict__ adj, const float* __restrict__ xt,
    const float* __restrict__ e1, const float* __restrict__ e2,
    float* __restrict__ out) {
  __shared__ int s_nbr[4][NCAP];
  __shared__ float s_p0[4][NCAP];
  __shared__ float s_p1[4][NCAP];

  const int wave = threadIdx.x >> 6;
  const int lane = threadIdx.x & 63;
  const int i = blockIdx.x * 4 + wave;   // this wave's row

  // ---- phase 1: scan row (16 float4/lane, all hoisted/in flight) ----
  const float4* row4 = (const float4*)(adj + (size_t)i * NN);
  float4 v[16];
#pragma unroll
  for (int c = 0; c < 16; ++c) v[c] = row4[lane + c * 64];

  const unsigned long long lt = (1ull << lane) - 1ull;
  int cnt = 0;
#pragma unroll
  for (int c = 0; c < 16; ++c) {
    float vals[4] = {v[c].x, v[c].y, v[c].z, v[c].w};
#pragma unroll
    for (int s = 0; s < 4; ++s) {
      int j = (c * 64 + lane) * 4 + s;
      bool hit = (vals[s] > 0.f) || (j == i);
      unsigned long long mask = __ballot(hit);
      if (hit) {
        int pos = cnt + (int)__popcll(mask & lt);
        if (pos < NCAP) s_nbr[wave][pos] = j;
      }
      cnt += (int)__popcll(mask);
    }
  }
  const int m = cnt < NCAP ? cnt : NCAP;

  // ---- phase 2: scores in registers (k = lane, lane+64) ----
  const float e10 = e1[i];
  const float e11 = e1[NN + i];
  float t0[2], t1[2];
  float mx0 = -3.0e38f, mx1 = -3.0e38f;
#pragma unroll
  for (int r = 0; r < 2; ++r) {
    int k = lane + r * 64;
    if (k < m) {
      int j = s_nbr[wave][k];
      t0[r] = lrelu(e10 + e2[j]);
      t1[r] = lrelu(e11 + e2[NN + j]);
      mx0 = fmaxf(mx0, t0[r]);
      mx1 = fmaxf(mx1, t1[r]);
    } else {
      t0[r] = -3.0e38f;
      t1[r] = -3.0e38f;
    }
  }
#pragma unroll
  for (int off = 32; off > 0; off >>= 1) {
    mx0 = fmaxf(mx0, __shfl_xor(mx0, off, 64));
    mx1 = fmaxf(mx1, __shfl_xor(mx1, off, 64));
  }

  // ---- phase 3: exp, write weights to LDS, wave-sum denominators ----
  float s0 = 0.f, s1 = 0.f;
#pragma unroll
  for (int r = 0; r < 2; ++r) {
    int k = lane + r * 64;
    if (k < m) {
      float p0 = __expf(t0[r] - mx0);
      float p1 = __expf(t1[r] - mx1);
      s_p0[wave][k] = p0;
      s_p1[wave][k] = p1;
      s0 += p0;
      s1 += p1;
    }
  }
#pragma unroll
  for (int off = 32; off > 0; off >>= 1) {
    s0 += __shfl_xor(s0, off, 64);
    s1 += __shfl_xor(s1, off, 64);
  }

  // ---- phase 4: gather-accumulate (float4/lane), x4 unrolled ----
  const int h = lane >> 5;
  const int o4 = (lane & 31) * 4;
  const float linv = 1.0f / (h ? s1 : s0);
  const float* pw = h ? s_p1[wave] : s_p0[wave];
  const int* nb = s_nbr[wave];
  const float* xth = xt + (size_t)h * NN * OUT_F + o4;

  f32x4 acc = (f32x4)(0.0f);
  int k = 0;
  for (; k + 4 <= m; k += 4) {
    int j0 = nb[k], j1 = nb[k + 1], j2 = nb[k + 2], j3 = nb[k + 3];
    float w0 = pw[k], w1 = pw[k + 1], w2 = pw[k + 2], w3 = pw[k + 3];
    f32x4 x0 = *(const f32x4*)(xth + (size_t)j0 * OUT_F);
    f32x4 x1 = *(const f32x4*)(xth + (size_t)j1 * OUT_F);
    f32x4 x2 = *(const f32x4*)(xth + (size_t)j2 * OUT_F);
    f32x4 x3 = *(const f32x4*)(xth + (size_t)j3 * OUT_F);
    acc += w0 * x0;
    acc += w1 * x1;
    acc += w2 * x2;
    acc += w3 * x3;
  }
  for (; k < m; ++k) {
    f32x4 xv = *(const f32x4*)(xth + (size_t)nb[k] * OUT_F);
    acc += pw[k] * xv;
  }

  // ---- epilogue: normalize, ELU, float4 store ----
  f32x4 r;
#pragma unroll
  for (int e = 0; e < 4; ++e) {
    float av = acc[e] * linv;
    r[e] = av > 0.f ? av : (__expf(av) - 1.0f);
  }
  *(f32x4*)(out + ((size_t)h * NN + i) * OUT_F + o4) = r;
}

// ---------------------------------------------------------------------------
extern "C" void kernel_launch(void* const* d_in, const int* in_sizes, int n_in,
                              void* d_out, int out_size, void* d_ws, size_t ws_size,
                              hipStream_t stream) {
  const float* x   = (const float*)d_in[0];
  const float* adj = (const float*)d_in[1];
  const float* W   = (const float*)d_in[2];
  const float* a   = (const float*)d_in[3];
  float* out = (float*)d_out;

  float* xt = (float*)d_ws;                                  // H*N*OUT_F f32 (4 MB)
  float* e1 = xt + (size_t)NHEAD * NN * OUT_F;               // H*N
  float* e2 = e1 + (size_t)NHEAD * NN;                       // H*N
  ushort* Wt = (ushort*)(e2 + (size_t)NHEAD * NN);           // H*OUT_F*IN_F bf16

  prep_w<<<64, 256, 0, stream>>>(W, Wt);
  gemm_mfma<<<dim3(NN / 32, NHEAD), 256, 0, stream>>>(x, Wt, a, xt, e1, e2);
  gat_aggregate<<<NN / 4, 256, 0, stream>>>(adj, xt, e1, e2, out);
}